// Round 6
// baseline (145.163 us; speedup 1.0000x reference)
//
#include <hip/hip_runtime.h>
#include <hip/hip_bf16.h>

#define BATCH 32
#define CIN   64
#define COUT  128
#define HIN   128
#define WIN   128
#define HOUT  64
#define WOUT  64

typedef unsigned int u32;
typedef __attribute__((ext_vector_type(8))) short short8;
typedef __attribute__((ext_vector_type(4))) float f32x4;

// ---------------- ws layout ----------------
// wsW  : byte      0 .. 262144 : bf16 weights, linear [16 chunks][128 o][64 k6]
// part : byte 262144 .. 786432 : [128][512] float2 partial sums
// ab   : byte 786432 .. 787456 : [128] float2 (scale, shift)

__device__ inline unsigned short f2bf(float v) {
  __hip_bfloat16 h = __float2bfloat16(v);
  return *reinterpret_cast<unsigned short*>(&h);
}
__device__ inline u32 pack2(float a, float b) {
  return (u32)f2bf(a) | ((u32)f2bf(b) << 16);
}

// ---------------- Kernel 1: Gabor filters -> linear bf16 ----------------
// k = i*16 + kh*4 + kw ; chunk c = i>>2 ; k6 = (i&3)*16 + kh*4 + kw
// wsW[(c*128 + o)*64 + k6]
__global__ __launch_bounds__(256) void gabor_kernel(
    const float* __restrict__ freq, const float* __restrict__ theta,
    const float* __restrict__ psi,  const float* __restrict__ sigma,
    __hip_bfloat16* __restrict__ wsw) {
  int idx = blockIdx.x * 256 + threadIdx.x;     // 8192 = 128*64
  int o = idx >> 6, i = idx & 63;
  float f = freq[idx], t = theta[idx], p = psi[idx], s = sigma[idx];
  float ct = cosf(t), st = sinf(t);
  float se = s + 0.001f;
  float gsc = -0.5f / (se * se);
  float nrm = 1.0f / (2.0f * 3.14f * s * s);    // PI = 3.14 in the reference
  const float lin[4] = {-1.f, 0.f, 1.f, 2.f};
  int chunk = i >> 2;
  #pragma unroll
  for (int ky = 0; ky < 4; ++ky) {
    #pragma unroll
    for (int kx = 0; kx < 4; ++kx) {
      float xx = lin[kx], yy = lin[ky];
      float rx =  xx * ct + yy * st;
      float ry = -xx * st + yy * ct;
      float g = __expf(gsc * (rx * rx + ry * ry)) * cosf(f * rx + p) * nrm;
      int k6 = (i & 3) * 16 + ky * 4 + kx;
      wsw[((size_t)(chunk * 128 + o)) * 64 + k6] = __float2bfloat16(g);
    }
  }
}

// ---------------- Kernel 2: implicit-GEMM conv via MFMA ----------------
// Block: 512 thr (8 waves, 2M x 4N split). Tile M=128 x N=256 (4 oh x 64 ow).
// Per wave: 64 (M) x 64 (N) = 4mf x 4nf fragments of 16x16.
// K loop: 16 chunks of 64 (4 input channels each). X double buffered in LDS;
// A fragments loaded straight from global (L2-resident 256 KiB).
constexpr int XPITCH = 70;    // dwords per x-tile row (140 bf16; ci = iw+3)
constexpr int XCH    = 700;   // dwords per channel plane (10 rows)
constexpr int XBYTES = 11200; // 4 ch * 700 dw * 4 B
constexpr int NSLOT  = 1360;  // 4 ch * 10 rows * 34 quads

__global__ __launch_bounds__(512, 4) void conv_mfma(
    const float* __restrict__ x, const char* __restrict__ wsW,
    float* __restrict__ out, float2* __restrict__ part) {
  __shared__ __align__(16) char lds[2 * XBYTES];

  const int tid = threadIdx.x;
  const int l = tid & 63, w = tid >> 6;       // 8 waves
  const int wm = w & 1, wn = w >> 1;          // wm: M-half, wn: N-quarter (0..3)
  const int t4 = l >> 4, lcol = l & 15;
  const int khp = t4 & 1, ihalf = t4 >> 1;
  const int ohb = blockIdx.x, b = blockIdx.y;
  const int oh0 = ohb * 4;

  // ---- staging precompute: 3 slots/thread, sg = tid + u*512 (0..1535 >= 1360) ----
  bool act[3]; int xdw[3]; const float* gp[3]; int vmask[3];
  #pragma unroll
  for (int u = 0; u < 3; ++u) {
    int sg = tid + u * 512;
    act[u] = sg < NSLOT;
    int r = sg / 34, s = sg - r * 34;      // quad s: cols 4s..4s+3 (iw = col-3)
    int ch = r / 10, row = r - ch * 10;
    int ih = oh0 * 2 - 1 + row;
    bool rok = act[u] && ((unsigned)ih < 128u);
    xdw[u] = ch * XCH + row * XPITCH + s * 2;
    gp[u] = x + (((size_t)(b * 64 + ch) << 14) + (size_t)ih * 128 + (4 * s - 3));
    int m = 0;
    #pragma unroll
    for (int e = 0; e < 4; ++e)
      if (rok && ((unsigned)(4 * s - 3 + e) < 128u)) m |= (1 << e);
    vmask[u] = m;
  }

  uint2 pk[3];
  auto XLOAD = [&](int c) {
    #pragma unroll
    for (int u = 0; u < 3; ++u) {
      const float* p = gp[u] + (size_t)c * 65536;    // 4 channels * 16384 floats
      float a0 = (vmask[u] & 1) ? p[0] : 0.f;
      float a1 = (vmask[u] & 2) ? p[1] : 0.f;
      float a2 = (vmask[u] & 4) ? p[2] : 0.f;
      float a3 = (vmask[u] & 8) ? p[3] : 0.f;
      pk[u].x = pack2(a0, a1);
      pk[u].y = pack2(a2, a3);
    }
  };
  auto XWRITE = [&](int nb) {
    u32* X = (u32*)(lds + nb * XBYTES);
    #pragma unroll
    for (int u = 0; u < 3; ++u)
      if (act[u]) *(uint2*)(X + xdw[u]) = pk[u];
  };

  f32x4 acc[4][4];
  #pragma unroll
  for (int mf = 0; mf < 4; ++mf)
    #pragma unroll
    for (int nf = 0; nf < 4; ++nf) acc[mf][nf] = {0.f, 0.f, 0.f, 0.f};

  // B-fragment dword offsets (within X buffer); nfb = 4*wn + nf in 0..15
  int bo[4];
  #pragma unroll
  for (int nf = 0; nf < 4; ++nf) {
    int nfb = 4 * wn + nf;
    bo[nf] = ihalf * XCH + khp * (2 * XPITCH) + lcol + 1 +
             (nfb >> 2) * (2 * XPITCH) + ((nfb & 3) << 4);
  }

  // A-fragment per-lane global base: row o = wm*64 + mf*16 + lcol, k6 = kk*32 + t4*8 + j
  const char* wl = wsW + wm * 8192 + lcol * 128 + t4 * 16;

  auto COMPUTE = [&](int c, int cb) {
    const char* wc = wl + c * 16384;
    const u32* Xb = (const u32*)(lds + cb * XBYTES);
    #pragma unroll
    for (int kk = 0; kk < 2; ++kk) {
      short8 af[4];
      #pragma unroll
      for (int mf = 0; mf < 4; ++mf)
        af[mf] = *(const short8*)(wc + mf * 2048 + kk * 64);
      #pragma unroll
      for (int nf = 0; nf < 4; ++nf) {
        const u32* p = Xb + bo[nf] + kk * 1400;      // 2 channel planes
        union { u32 u[4]; short8 s8; } bu;
        bu.u[0] = p[0]; bu.u[1] = p[1];
        bu.u[2] = p[XPITCH]; bu.u[3] = p[XPITCH + 1];
        short8 bf = bu.s8;
        #pragma unroll
        for (int mf = 0; mf < 4; ++mf)
          acc[mf][nf] = __builtin_amdgcn_mfma_f32_16x16x32_bf16(af[mf], bf, acc[mf][nf], 0, 0, 0);
      }
    }
  };

  // ---- main loop: X double-buffered, A straight from global ----
  XLOAD(0); XWRITE(0);
  __syncthreads();
  for (int c = 0; c < 16; ++c) {
    int cur = c & 1;
    if (c < 15) XLOAD(c + 1);          // issue next-tile global loads early
    COMPUTE(c, cur);                   // latency hides under MFMA + ds_reads
    if (c < 15) XWRITE(cur ^ 1);
    __syncthreads();
  }

  // ---- epilogue: conv output (C/D layout: col=lane&15, row=(lane>>4)*4+reg) ----
  size_t obase = ((size_t)b * 128) * 4096;
  #pragma unroll
  for (int mf = 0; mf < 4; ++mf)
    #pragma unroll
    for (int nf = 0; nf < 4; ++nf) {
      int nfb = 4 * wn + nf;
      int oh = oh0 + (nfb >> 2), ow = ((nfb & 3) << 4) + lcol;
      #pragma unroll
      for (int r = 0; r < 4; ++r) {
        int o = wm * 64 + mf * 16 + t4 * 4 + r;
        out[obase + (size_t)o * 4096 + oh * 64 + ow] = acc[mf][nf][r];
      }
    }

  // ---- deterministic per-block (sum, sumsq) partials ----
  float* ps = (float*)lds;    // reuse LDS: [128 o][4 wn][2] floats = 4 KiB
  #pragma unroll
  for (int mf = 0; mf < 4; ++mf)
    #pragma unroll
    for (int r = 0; r < 4; ++r) {
      float s1 = 0.f, s2 = 0.f;
      #pragma unroll
      for (int nf = 0; nf < 4; ++nf) { float v = acc[mf][nf][r]; s1 += v; s2 += v * v; }
      #pragma unroll
      for (int d = 1; d < 16; d <<= 1) { s1 += __shfl_xor(s1, d); s2 += __shfl_xor(s2, d); }
      if (lcol == 0) {
        int o = wm * 64 + mf * 16 + t4 * 4 + r;
        ps[o * 8 + wn * 2 + 0] = s1;
        ps[o * 8 + wn * 2 + 1] = s2;
      }
    }
  __syncthreads();
  if (tid < 128) {
    float s1 = 0.f, s2 = 0.f;
    #pragma unroll
    for (int q = 0; q < 4; ++q) {
      s1 += ps[tid * 8 + q * 2 + 0];
      s2 += ps[tid * 8 + q * 2 + 1];
    }
    part[(size_t)tid * 512 + b * 16 + ohb] = make_float2(s1, s2);
  }
}

// ---------------- Kernel 3: per-channel stats -> (a,b) ----------------
__global__ __launch_bounds__(256) void stats_kernel(
    const float2* __restrict__ part, const float* __restrict__ gamma,
    const float* __restrict__ beta, float2* __restrict__ ab) {
  int o = blockIdx.x;
  int tid = threadIdx.x;
  float s1 = 0.f, s2 = 0.f;
  #pragma unroll
  for (int t = 0; t < 2; ++t) {
    float2 p = part[(size_t)o * 512 + tid + t * 256];
    s1 += p.x; s2 += p.y;
  }
  __shared__ float r1[256], r2[256];
  r1[tid] = s1; r2[tid] = s2;
  __syncthreads();
  for (int off = 128; off > 0; off >>= 1) {
    if (tid < off) { r1[tid] += r1[tid + off]; r2[tid] += r2[tid + off]; }
    __syncthreads();
  }
  if (tid == 0) {
    const float N = (float)BATCH * HOUT * WOUT;   // 131072
    float mean = r1[0] / N;
    float var  = r2[0] / N - mean * mean;
    float inv  = rsqrtf(var + 1e-5f);
    float a = gamma[o] * inv;
    float bb = beta[o] - mean * a;
    ab[o] = make_float2(a, bb);
  }
}

// ---------------- Kernel 4: normalize + leaky ReLU (in-place, float4) ----------------
__global__ __launch_bounds__(256) void norm_kernel(
    float* __restrict__ out, const float2* __restrict__ ab) {
  size_t idx = (size_t)blockIdx.x * 256 + threadIdx.x;   // float4 index
  int o = (int)((idx >> 10) & (COUT - 1));               // 1024 float4 per (b,o) plane
  float2 s = ab[o];
  float4 v = reinterpret_cast<float4*>(out)[idx];
  v.x = fmaf(v.x, s.x, s.y);
  v.y = fmaf(v.y, s.x, s.y);
  v.z = fmaf(v.z, s.x, s.y);
  v.w = fmaf(v.w, s.x, s.y);
  v.x = v.x >= 0.f ? v.x : 0.1f * v.x;
  v.y = v.y >= 0.f ? v.y : 0.1f * v.y;
  v.z = v.z >= 0.f ? v.z : 0.1f * v.z;
  v.w = v.w >= 0.f ? v.w : 0.1f * v.w;
  reinterpret_cast<float4*>(out)[idx] = v;
}

extern "C" void kernel_launch(void* const* d_in, const int* in_sizes, int n_in,
                              void* d_out, int out_size, void* d_ws, size_t ws_size,
                              hipStream_t stream) {
  const float* x     = (const float*)d_in[0];
  const float* freq  = (const float*)d_in[1];
  const float* theta = (const float*)d_in[2];
  const float* psi   = (const float*)d_in[3];
  const float* sigma = (const float*)d_in[4];
  const float* gamma = (const float*)d_in[5];
  const float* beta  = (const float*)d_in[6];
  float* out = (float*)d_out;

  __hip_bfloat16* wsw = (__hip_bfloat16*)d_ws;
  float2* part = (float2*)((char*)d_ws + 262144);
  float2* ab   = (float2*)((char*)d_ws + 786432);

  gabor_kernel<<<32, 256, 0, stream>>>(freq, theta, psi, sigma, wsw);
  conv_mfma<<<dim3(16, BATCH), 512, 0, stream>>>(x, (const char*)d_ws, out, part);
  stats_kernel<<<COUT, 256, 0, stream>>>(part, gamma, beta, ab);
  norm_kernel<<<4194304 / 256, 256, 0, stream>>>(out, ab);
}

// Round 7
// 112.929 us; speedup vs baseline: 1.2854x; 1.2854x over previous
//
#include <hip/hip_runtime.h>
#include <hip/hip_bf16.h>

#define BATCH 32
#define CIN   64
#define COUT  128
#define HIN   128
#define WIN   128
#define HOUT  64
#define WOUT  64

typedef unsigned int u32;
typedef __attribute__((ext_vector_type(8))) short short8;
typedef __attribute__((ext_vector_type(4))) float f32x4;

// ---------------- ws layout ----------------
// wsW  : byte      0 .. 262144 : bf16 weights, linear [16 chunks][128 o][64 k6]
// part : byte 262144 .. 786432 : [128][512] float2 partial sums
// ab   : byte 786432 .. 787456 : [128] float2 (scale, shift)

__device__ inline unsigned short f2bf(float v) {
  __hip_bfloat16 h = __float2bfloat16(v);
  return *reinterpret_cast<unsigned short*>(&h);
}
__device__ inline u32 pack2(float a, float b) {
  return (u32)f2bf(a) | ((u32)f2bf(b) << 16);
}

// ---------------- Kernel 1: Gabor filters -> linear bf16 (verified round 5) ----------------
// k = i*16 + kh*4 + kw ; chunk c = i>>2 ; k6 = (i&3)*16 + kh*4 + kw
// wsW[(c*128 + o)*64 + k6]
__global__ __launch_bounds__(256) void gabor_kernel(
    const float* __restrict__ freq, const float* __restrict__ theta,
    const float* __restrict__ psi,  const float* __restrict__ sigma,
    __hip_bfloat16* __restrict__ wsw) {
  int idx = blockIdx.x * 256 + threadIdx.x;     // 8192 = 128*64
  int o = idx >> 6, i = idx & 63;
  float f = freq[idx], t = theta[idx], p = psi[idx], s = sigma[idx];
  float ct = cosf(t), st = sinf(t);
  float se = s + 0.001f;
  float gsc = -0.5f / (se * se);
  float nrm = 1.0f / (2.0f * 3.14f * s * s);    // PI = 3.14 in the reference
  const float lin[4] = {-1.f, 0.f, 1.f, 2.f};
  int chunk = i >> 2;
  #pragma unroll
  for (int ky = 0; ky < 4; ++ky) {
    #pragma unroll
    for (int kx = 0; kx < 4; ++kx) {
      float xx = lin[kx], yy = lin[ky];
      float rx =  xx * ct + yy * st;
      float ry = -xx * st + yy * ct;
      float g = __expf(gsc * (rx * rx + ry * ry)) * cosf(f * rx + p) * nrm;
      int k6 = (i & 3) * 16 + ky * 4 + kx;
      wsw[((size_t)(chunk * 128 + o)) * 64 + k6] = __float2bfloat16(g);
    }
  }
}

// ---------------- Kernel 2: implicit-GEMM conv via MFMA ----------------
// Block: 512 thr (8 waves, 2M x 4N). Tile M=128 x N=256 (4 oh x 64 ow).
// K loop: 16 chunks of 64 (4 input channels). A and X double-buffered in LDS.
// A staged coalesced (reg-stage + XOR-swizzled ds_write_b128):
//   lds byte = p ^ (((p>>7)&7)<<4), p = linear chunk offset (o*128 + k6*2).
constexpr int XPITCH = 70;    // dwords per x-tile row (140 bf16; ci = iw+3)
constexpr int XCH    = 700;   // dwords per channel plane (10 rows)
constexpr int XBYTES = 11200; // 4 ch * 700 dw * 4 B
constexpr int NSLOT  = 1360;  // 4 ch * 10 rows * 34 quads
// LDS: A0 @0, A1 @16384, X0 @32768, X1 @43968 ; total 55168

__global__ __launch_bounds__(512, 4) void conv_mfma(
    const float* __restrict__ x, const char* __restrict__ wsW,
    float* __restrict__ out, float2* __restrict__ part) {
  __shared__ __align__(16) char lds[55168];

  const int tid = threadIdx.x;
  const int l = tid & 63, w = tid >> 6;       // 8 waves
  const int wm = w & 1, wn = w >> 1;          // wm: M-half, wn: N-quarter (0..3)
  const int t4 = l >> 4, lcol = l & 15;
  const int khp = t4 & 1, ihalf = t4 >> 1;
  const int ohb = blockIdx.x, b = blockIdx.y;
  const int oh0 = ohb * 4;

  // ---- X staging precompute: 3 slots/thread, sg = tid + u*512 (0..1535 >= 1360) ----
  bool act[3]; int xdw[3]; const float* gp[3]; int vmask[3];
  #pragma unroll
  for (int u = 0; u < 3; ++u) {
    int sg = tid + u * 512;
    act[u] = sg < NSLOT;
    int r = sg / 34, s = sg - r * 34;      // quad s: cols 4s..4s+3 (iw = col-3)
    int ch = r / 10, row = r - ch * 10;
    int ih = oh0 * 2 - 1 + row;
    bool rok = act[u] && ((unsigned)ih < 128u);
    xdw[u] = ch * XCH + row * XPITCH + s * 2;
    gp[u] = x + (((size_t)(b * 64 + ch) << 14) + (size_t)ih * 128 + (4 * s - 3));
    int m = 0;
    #pragma unroll
    for (int e = 0; e < 4; ++e)
      if (rok && ((unsigned)(4 * s - 3 + e) < 128u)) m |= (1 << e);
    vmask[u] = m;
  }

  uint2 pk[3];
  auto XLOAD = [&](int c) {
    #pragma unroll
    for (int u = 0; u < 3; ++u) {
      const float* p = gp[u] + (size_t)c * 65536;    // 4 channels * 16384 floats
      float a0 = (vmask[u] & 1) ? p[0] : 0.f;
      float a1 = (vmask[u] & 2) ? p[1] : 0.f;
      float a2 = (vmask[u] & 4) ? p[2] : 0.f;
      float a3 = (vmask[u] & 8) ? p[3] : 0.f;
      pk[u].x = pack2(a0, a1);
      pk[u].y = pack2(a2, a3);
    }
  };
  auto XWRITE = [&](int nb) {
    u32* X = (u32*)(lds + 32768 + nb * XBYTES);
    #pragma unroll
    for (int u = 0; u < 3; ++u)
      if (act[u]) *(uint2*)(X + xdw[u]) = pk[u];
  };

  // ---- A staging: thread tid owns 32 contiguous bytes of the 16 KiB chunk ----
  uint4 areg0, areg1;
  const int abase = tid * 32;                        // p, p+16 share row o = tid>>2
  const int aswz  = ((tid >> 2) & 7) << 4;           // XOR swizzle ((p>>7)&7)<<4
  auto ALOAD = [&](int c) {
    const uint4* src = (const uint4*)(wsW + c * 16384 + abase);
    areg0 = src[0]; areg1 = src[1];                  // coalesced dwordx4 x2
  };
  auto AWRITE = [&](int nb) {
    char* A = lds + nb * 16384;
    *(uint4*)(A + (abase ^ aswz))        = areg0;
    *(uint4*)(A + ((abase + 16) ^ aswz)) = areg1;
  };

  f32x4 acc[4][4];
  #pragma unroll
  for (int mf = 0; mf < 4; ++mf)
    #pragma unroll
    for (int nf = 0; nf < 4; ++nf) acc[mf][nf] = {0.f, 0.f, 0.f, 0.f};

  // B-fragment dword offsets (within X buffer); nfb = 4*wn + nf in 0..15
  int bo[4];
  #pragma unroll
  for (int nf = 0; nf < 4; ++nf) {
    int nfb = 4 * wn + nf;
    bo[nf] = ihalf * XCH + khp * (2 * XPITCH) + lcol + 1 +
             (nfb >> 2) * (2 * XPITCH) + ((nfb & 3) << 4);
  }

  // A-fragment LDS offsets: row o = wm*64 + mf*16 + lcol, subtile (4*kk + t4),
  // swizzled: byte = o*128 + ((4*kk + t4) ^ (o&7))*16
  int ao[4][2];
  #pragma unroll
  for (int mf = 0; mf < 4; ++mf)
    #pragma unroll
    for (int kk = 0; kk < 2; ++kk)
      ao[mf][kk] = (wm * 64 + mf * 16 + lcol) * 128 +
                   (((4 * kk + t4) ^ (lcol & 7)) << 4);

  auto COMPUTE = [&](int cb) {
    const char* Ab = lds + cb * 16384;
    const u32* Xb = (const u32*)(lds + 32768 + cb * XBYTES);
    #pragma unroll
    for (int kk = 0; kk < 2; ++kk) {
      short8 af[4];
      #pragma unroll
      for (int mf = 0; mf < 4; ++mf)
        af[mf] = *(const short8*)(Ab + ao[mf][kk]);
      #pragma unroll
      for (int nf = 0; nf < 4; ++nf) {
        const u32* p = Xb + bo[nf] + kk * 1400;      // 2 channel planes
        union { u32 u[4]; short8 s8; } bu;
        bu.u[0] = p[0]; bu.u[1] = p[1];
        bu.u[2] = p[XPITCH]; bu.u[3] = p[XPITCH + 1];
        short8 bf = bu.s8;
        #pragma unroll
        for (int mf = 0; mf < 4; ++mf)
          acc[mf][nf] = __builtin_amdgcn_mfma_f32_16x16x32_bf16(af[mf], bf, acc[mf][nf], 0, 0, 0);
      }
    }
  };

  // ---- main loop: A+X double-buffered, loads issued early ----
  ALOAD(0); XLOAD(0); AWRITE(0); XWRITE(0);
  __syncthreads();
  for (int c = 0; c < 16; ++c) {
    int cur = c & 1;
    if (c < 15) { ALOAD(c + 1); XLOAD(c + 1); }   // global loads in flight
    COMPUTE(cur);                                  // LDS reads + MFMA cover latency
    if (c < 15) { AWRITE(cur ^ 1); XWRITE(cur ^ 1); }
    __syncthreads();
  }

  // ---- epilogue: conv output (C/D layout: col=lane&15, row=(lane>>4)*4+reg) ----
  size_t obase = ((size_t)b * 128) * 4096;
  #pragma unroll
  for (int mf = 0; mf < 4; ++mf)
    #pragma unroll
    for (int nf = 0; nf < 4; ++nf) {
      int nfb = 4 * wn + nf;
      int oh = oh0 + (nfb >> 2), ow = ((nfb & 3) << 4) + lcol;
      #pragma unroll
      for (int r = 0; r < 4; ++r) {
        int o = wm * 64 + mf * 16 + t4 * 4 + r;
        out[obase + (size_t)o * 4096 + oh * 64 + ow] = acc[mf][nf][r];
      }
    }

  // ---- deterministic per-block (sum, sumsq) partials ----
  // (loop ended with __syncthreads; A0 region is dead -> reuse as scratch)
  float* ps = (float*)lds;    // [128 o][4 wn][2] floats = 4 KiB
  #pragma unroll
  for (int mf = 0; mf < 4; ++mf)
    #pragma unroll
    for (int r = 0; r < 4; ++r) {
      float s1 = 0.f, s2 = 0.f;
      #pragma unroll
      for (int nf = 0; nf < 4; ++nf) { float v = acc[mf][nf][r]; s1 += v; s2 += v * v; }
      #pragma unroll
      for (int d = 1; d < 16; d <<= 1) { s1 += __shfl_xor(s1, d); s2 += __shfl_xor(s2, d); }
      if (lcol == 0) {
        int o = wm * 64 + mf * 16 + t4 * 4 + r;
        ps[o * 8 + wn * 2 + 0] = s1;
        ps[o * 8 + wn * 2 + 1] = s2;
      }
    }
  __syncthreads();
  if (tid < 128) {
    float s1 = 0.f, s2 = 0.f;
    #pragma unroll
    for (int q = 0; q < 4; ++q) {
      s1 += ps[tid * 8 + q * 2 + 0];
      s2 += ps[tid * 8 + q * 2 + 1];
    }
    part[(size_t)tid * 512 + b * 16 + ohb] = make_float2(s1, s2);
  }
}

// ---------------- Kernel 3: per-channel stats -> (a,b) ----------------
__global__ __launch_bounds__(256) void stats_kernel(
    const float2* __restrict__ part, const float* __restrict__ gamma,
    const float* __restrict__ beta, float2* __restrict__ ab) {
  int o = blockIdx.x;
  int tid = threadIdx.x;
  float s1 = 0.f, s2 = 0.f;
  #pragma unroll
  for (int t = 0; t < 2; ++t) {
    float2 p = part[(size_t)o * 512 + tid + t * 256];
    s1 += p.x; s2 += p.y;
  }
  __shared__ float r1[256], r2[256];
  r1[tid] = s1; r2[tid] = s2;
  __syncthreads();
  for (int off = 128; off > 0; off >>= 1) {
    if (tid < off) { r1[tid] += r1[tid + off]; r2[tid] += r2[tid + off]; }
    __syncthreads();
  }
  if (tid == 0) {
    const float N = (float)BATCH * HOUT * WOUT;   // 131072
    float mean = r1[0] / N;
    float var  = r2[0] / N - mean * mean;
    float inv  = rsqrtf(var + 1e-5f);
    float a = gamma[o] * inv;
    float bb = beta[o] - mean * a;
    ab[o] = make_float2(a, bb);
  }
}

// ---------------- Kernel 4: normalize + leaky ReLU (in-place, float4) ----------------
__global__ __launch_bounds__(256) void norm_kernel(
    float* __restrict__ out, const float2* __restrict__ ab) {
  size_t idx = (size_t)blockIdx.x * 256 + threadIdx.x;   // float4 index
  int o = (int)((idx >> 10) & (COUT - 1));               // 1024 float4 per (b,o) plane
  float2 s = ab[o];
  float4 v = reinterpret_cast<float4*>(out)[idx];
  v.x = fmaf(v.x, s.x, s.y);
  v.y = fmaf(v.y, s.x, s.y);
  v.z = fmaf(v.z, s.x, s.y);
  v.w = fmaf(v.w, s.x, s.y);
  v.x = v.x >= 0.f ? v.x : 0.1f * v.x;
  v.y = v.y >= 0.f ? v.y : 0.1f * v.y;
  v.z = v.z >= 0.f ? v.z : 0.1f * v.z;
  v.w = v.w >= 0.f ? v.w : 0.1f * v.w;
  reinterpret_cast<float4*>(out)[idx] = v;
}

extern "C" void kernel_launch(void* const* d_in, const int* in_sizes, int n_in,
                              void* d_out, int out_size, void* d_ws, size_t ws_size,
                              hipStream_t stream) {
  const float* x     = (const float*)d_in[0];
  const float* freq  = (const float*)d_in[1];
  const float* theta = (const float*)d_in[2];
  const float* psi   = (const float*)d_in[3];
  const float* sigma = (const float*)d_in[4];
  const float* gamma = (const float*)d_in[5];
  const float* beta  = (const float*)d_in[6];
  float* out = (float*)d_out;

  __hip_bfloat16* wsw = (__hip_bfloat16*)d_ws;
  float2* part = (float2*)((char*)d_ws + 262144);
  float2* ab   = (float2*)((char*)d_ws + 786432);

  gabor_kernel<<<32, 256, 0, stream>>>(freq, theta, psi, sigma, wsw);
  conv_mfma<<<dim3(16, BATCH), 512, 0, stream>>>(x, (const char*)d_ws, out, part);
  stats_kernel<<<COUT, 256, 0, stream>>>(part, gamma, beta, ab);
  norm_kernel<<<4194304 / 256, 256, 0, stream>>>(out, ab);
}

// Round 8
// 80.148 us; speedup vs baseline: 1.8112x; 1.4090x over previous
//
#include <hip/hip_runtime.h>
#include <hip/hip_bf16.h>

#define BATCH 32
#define CIN   64
#define COUT  128
#define HIN   128
#define WIN   128
#define HOUT  64
#define WOUT  64

typedef unsigned int u32;
typedef __attribute__((ext_vector_type(8))) short short8;
typedef __attribute__((ext_vector_type(4))) float f32x4;

// ---------------- ws layout ----------------
// wsW  : byte      0 .. 262144 : bf16 weights, linear [16 chunks][128 o][64 k6]
// part : byte 262144 .. 786432 : [128][512] float2 partial sums
// ab   : byte 786432 .. 787456 : [128] float2 (scale, shift)

__device__ inline unsigned short f2bf(float v) {
  __hip_bfloat16 h = __float2bfloat16(v);
  return *reinterpret_cast<unsigned short*>(&h);
}
__device__ inline u32 pack2(float a, float b) {
  return (u32)f2bf(a) | ((u32)f2bf(b) << 16);
}

// ---------------- Kernel 1: Gabor filters -> linear bf16 (verified) ----------------
// k = i*16 + kh*4 + kw ; chunk c = i>>2 ; k6 = (i&3)*16 + kh*4 + kw
// wsW[(c*128 + o)*64 + k6]
__global__ __launch_bounds__(256) void gabor_kernel(
    const float* __restrict__ freq, const float* __restrict__ theta,
    const float* __restrict__ psi,  const float* __restrict__ sigma,
    __hip_bfloat16* __restrict__ wsw) {
  int idx = blockIdx.x * 256 + threadIdx.x;     // 8192 = 128*64
  int o = idx >> 6, i = idx & 63;
  float f = freq[idx], t = theta[idx], p = psi[idx], s = sigma[idx];
  float ct = cosf(t), st = sinf(t);
  float se = s + 0.001f;
  float gsc = -0.5f / (se * se);
  float nrm = 1.0f / (2.0f * 3.14f * s * s);    // PI = 3.14 in the reference
  const float lin[4] = {-1.f, 0.f, 1.f, 2.f};
  int chunk = i >> 2;
  #pragma unroll
  for (int ky = 0; ky < 4; ++ky) {
    #pragma unroll
    for (int kx = 0; kx < 4; ++kx) {
      float xx = lin[kx], yy = lin[ky];
      float rx =  xx * ct + yy * st;
      float ry = -xx * st + yy * ct;
      float g = __expf(gsc * (rx * rx + ry * ry)) * cosf(f * rx + p) * nrm;
      int k6 = (i & 3) * 16 + ky * 4 + kx;
      wsw[((size_t)(chunk * 128 + o)) * 64 + k6] = __float2bfloat16(g);
    }
  }
}

// ---------------- Kernel 2: implicit-GEMM conv via MFMA ----------------
// Block: 512 thr (8 waves, 2M x 4N). Tile M=128 x N=256 (4 oh x 64 ow).
// K loop: 16 chunks of 64 (4 input channels). A and X double-buffered in LDS.
// X staged via ALIGNED float4 global loads (iw = 4s..4s+3), the +3 pad shift is
// applied in the LDS write addressing (b16@+6, b32@+8, b16@+12). Edge zeros
// (ci 0..2, 131) and OOB rows are zero-filled once at init, never rewritten.
constexpr int XPITCH = 70;    // dwords per x-tile row (140 bf16; ci = iw+3)
constexpr int XCH    = 700;   // dwords per channel plane (10 rows)
constexpr int XBYTES = 11200; // 4 ch * 700 dw * 4 B
constexpr int NSLOT  = 1280;  // 4 ch * 10 rows * 32 aligned quads
// LDS: A0 @0, A1 @16384, X0 @32768, X1 @43968 ; total 55168

__global__ __launch_bounds__(512, 4) void conv_mfma(
    const float* __restrict__ x, const char* __restrict__ wsW,
    float* __restrict__ out, float2* __restrict__ part) {
  __shared__ __align__(16) char lds[55168];

  const int tid = threadIdx.x;
  const int l = tid & 63, w = tid >> 6;       // 8 waves
  const int wm = w & 1, wn = w >> 1;          // wm: M-half, wn: N-quarter (0..3)
  const int t4 = l >> 4, lcol = l & 15;
  const int khp = t4 & 1, ihalf = t4 >> 1;
  const int ohb = blockIdx.x, b = blockIdx.y;
  const int oh0 = ohb * 4;

  // ---- X staging precompute: 3 slots/thread, sg = tid + u*512 (covers 1280) ----
  bool act[3]; int xbyte[3]; const float* gp[3];
  #pragma unroll
  for (int u = 0; u < 3; ++u) {
    int sg = tid + u * 512;
    int r = sg >> 5, s = sg & 31;          // row r (0..39), aligned quad s (0..31)
    int ch = r / 10, row = r - ch * 10;
    int ih = oh0 * 2 - 1 + row;
    act[u] = (sg < NSLOT) && ((unsigned)ih < 128u);
    xbyte[u] = (ch * XCH + row * XPITCH) * 4 + s * 8;
    gp[u] = x + (((size_t)(b * 64 + ch) << 14) + (size_t)ih * 128 + 4 * s);
  }

  float4 xv[3];
  auto XLOAD = [&](int c) {
    #pragma unroll
    for (int u = 0; u < 3; ++u)
      if (act[u]) xv[u] = *(const float4*)(gp[u] + (size_t)c * 65536);
  };
  auto XWRITE = [&](int nb) {
    char* X = lds + 32768 + nb * XBYTES;
    #pragma unroll
    for (int u = 0; u < 3; ++u)
      if (act[u]) {
        char* pb = X + xbyte[u];
        *(unsigned short*)(pb + 6)  = f2bf(xv[u].x);       // ci 4s+3
        *(u32*)(pb + 8)             = pack2(xv[u].y, xv[u].z); // ci 4s+4,4s+5
        *(unsigned short*)(pb + 12) = f2bf(xv[u].w);       // ci 4s+6
      }
  };

  // ---- A staging: thread tid owns 32 contiguous bytes of the 16 KiB chunk ----
  uint4 areg0, areg1;
  const int abase = tid * 32;                        // p, p+16 share row o = tid>>2
  const int aswz  = ((tid >> 2) & 7) << 4;           // XOR swizzle ((p>>7)&7)<<4
  auto ALOAD = [&](int c) {
    const uint4* src = (const uint4*)(wsW + c * 16384 + abase);
    areg0 = src[0]; areg1 = src[1];                  // coalesced dwordx4 x2
  };
  auto AWRITE = [&](int nb) {
    char* A = lds + nb * 16384;
    *(uint4*)(A + (abase ^ aswz))        = areg0;
    *(uint4*)(A + ((abase + 16) ^ aswz)) = areg1;
  };

  // ---- one-time zero fill of both X buffers (edges + OOB rows stay zero) ----
  {
    u32* X = (u32*)(lds + 32768);
    for (int i = tid; i < 2 * XBYTES / 4; i += 512) X[i] = 0;
  }

  f32x4 acc[4][4];
  #pragma unroll
  for (int mf = 0; mf < 4; ++mf)
    #pragma unroll
    for (int nf = 0; nf < 4; ++nf) acc[mf][nf] = {0.f, 0.f, 0.f, 0.f};

  // B-fragment dword offsets (within X buffer); nfb = 4*wn + nf in 0..15
  int bo[4];
  #pragma unroll
  for (int nf = 0; nf < 4; ++nf) {
    int nfb = 4 * wn + nf;
    bo[nf] = ihalf * XCH + khp * (2 * XPITCH) + lcol + 1 +
             (nfb >> 2) * (2 * XPITCH) + ((nfb & 3) << 4);
  }

  // A-fragment LDS offsets: row o = wm*64 + mf*16 + lcol, subtile (4*kk + t4),
  // swizzled: byte = o*128 + ((4*kk + t4) ^ (o&7))*16
  int ao[4][2];
  #pragma unroll
  for (int mf = 0; mf < 4; ++mf)
    #pragma unroll
    for (int kk = 0; kk < 2; ++kk)
      ao[mf][kk] = (wm * 64 + mf * 16 + lcol) * 128 +
                   (((4 * kk + t4) ^ (lcol & 7)) << 4);

  auto COMPUTE = [&](int cb) {
    const char* Ab = lds + cb * 16384;
    const u32* Xb = (const u32*)(lds + 32768 + cb * XBYTES);
    #pragma unroll
    for (int kk = 0; kk < 2; ++kk) {
      short8 af[4];
      #pragma unroll
      for (int mf = 0; mf < 4; ++mf)
        af[mf] = *(const short8*)(Ab + ao[mf][kk]);
      #pragma unroll
      for (int nf = 0; nf < 4; ++nf) {
        const u32* p = Xb + bo[nf] + kk * 1400;      // 2 channel planes
        union { u32 u[4]; short8 s8; } bu;
        bu.u[0] = p[0]; bu.u[1] = p[1];
        bu.u[2] = p[XPITCH]; bu.u[3] = p[XPITCH + 1];
        short8 bf = bu.s8;
        #pragma unroll
        for (int mf = 0; mf < 4; ++mf)
          acc[mf][nf] = __builtin_amdgcn_mfma_f32_16x16x32_bf16(af[mf], bf, acc[mf][nf], 0, 0, 0);
      }
    }
  };

  // ---- main loop: A+X double-buffered, loads issued early ----
  ALOAD(0); XLOAD(0);
  __syncthreads();                 // zero-fill visible before first writes
  AWRITE(0); XWRITE(0);
  __syncthreads();
  for (int c = 0; c < 16; ++c) {
    int cur = c & 1;
    if (c < 15) { ALOAD(c + 1); XLOAD(c + 1); }   // global loads in flight
    COMPUTE(cur);                                  // LDS reads + MFMA cover latency
    if (c < 15) { AWRITE(cur ^ 1); XWRITE(cur ^ 1); }
    __syncthreads();
  }

  // ---- epilogue: conv output (C/D layout: col=lane&15, row=(lane>>4)*4+reg) ----
  size_t obase = ((size_t)b * 128) * 4096;
  #pragma unroll
  for (int mf = 0; mf < 4; ++mf)
    #pragma unroll
    for (int nf = 0; nf < 4; ++nf) {
      int nfb = 4 * wn + nf;
      int oh = oh0 + (nfb >> 2), ow = ((nfb & 3) << 4) + lcol;
      #pragma unroll
      for (int r = 0; r < 4; ++r) {
        int o = wm * 64 + mf * 16 + t4 * 4 + r;
        out[obase + (size_t)o * 4096 + oh * 64 + ow] = acc[mf][nf][r];
      }
    }

  // ---- deterministic per-block (sum, sumsq) partials ----
  float* ps = (float*)lds;    // A0 region dead after last barrier
  #pragma unroll
  for (int mf = 0; mf < 4; ++mf)
    #pragma unroll
    for (int r = 0; r < 4; ++r) {
      float s1 = 0.f, s2 = 0.f;
      #pragma unroll
      for (int nf = 0; nf < 4; ++nf) { float v = acc[mf][nf][r]; s1 += v; s2 += v * v; }
      #pragma unroll
      for (int d = 1; d < 16; d <<= 1) { s1 += __shfl_xor(s1, d); s2 += __shfl_xor(s2, d); }
      if (lcol == 0) {
        int o = wm * 64 + mf * 16 + t4 * 4 + r;
        ps[o * 8 + wn * 2 + 0] = s1;
        ps[o * 8 + wn * 2 + 1] = s2;
      }
    }
  __syncthreads();
  if (tid < 128) {
    float s1 = 0.f, s2 = 0.f;
    #pragma unroll
    for (int q = 0; q < 4; ++q) {
      s1 += ps[tid * 8 + q * 2 + 0];
      s2 += ps[tid * 8 + q * 2 + 1];
    }
    part[(size_t)tid * 512 + b * 16 + ohb] = make_float2(s1, s2);
  }
}

// ---------------- Kernel 3: per-channel stats -> (a,b) ----------------
__global__ __launch_bounds__(256) void stats_kernel(
    const float2* __restrict__ part, const float* __restrict__ gamma,
    const float* __restrict__ beta, float2* __restrict__ ab) {
  int o = blockIdx.x;
  int tid = threadIdx.x;
  float s1 = 0.f, s2 = 0.f;
  #pragma unroll
  for (int t = 0; t < 2; ++t) {
    float2 p = part[(size_t)o * 512 + tid + t * 256];
    s1 += p.x; s2 += p.y;
  }
  __shared__ float r1[256], r2[256];
  r1[tid] = s1; r2[tid] = s2;
  __syncthreads();
  for (int off = 128; off > 0; off >>= 1) {
    if (tid < off) { r1[tid] += r1[tid + off]; r2[tid] += r2[tid + off]; }
    __syncthreads();
  }
  if (tid == 0) {
    const float N = (float)BATCH * HOUT * WOUT;   // 131072
    float mean = r1[0] / N;
    float var  = r2[0] / N - mean * mean;
    float inv  = rsqrtf(var + 1e-5f);
    float a = gamma[o] * inv;
    float bb = beta[o] - mean * a;
    ab[o] = make_float2(a, bb);
  }
}

// ---------------- Kernel 4: normalize + leaky ReLU (in-place, float4) ----------------
__global__ __launch_bounds__(256) void norm_kernel(
    float* __restrict__ out, const float2* __restrict__ ab) {
  size_t idx = (size_t)blockIdx.x * 256 + threadIdx.x;   // float4 index
  int o = (int)((idx >> 10) & (COUT - 1));               // 1024 float4 per (b,o) plane
  float2 s = ab[o];
  float4 v = reinterpret_cast<float4*>(out)[idx];
  v.x = fmaf(v.x, s.x, s.y);
  v.y = fmaf(v.y, s.x, s.y);
  v.z = fmaf(v.z, s.x, s.y);
  v.w = fmaf(v.w, s.x, s.y);
  v.x = v.x >= 0.f ? v.x : 0.1f * v.x;
  v.y = v.y >= 0.f ? v.y : 0.1f * v.y;
  v.z = v.z >= 0.f ? v.z : 0.1f * v.z;
  v.w = v.w >= 0.f ? v.w : 0.1f * v.w;
  reinterpret_cast<float4*>(out)[idx] = v;
}

extern "C" void kernel_launch(void* const* d_in, const int* in_sizes, int n_in,
                              void* d_out, int out_size, void* d_ws, size_t ws_size,
                              hipStream_t stream) {
  const float* x     = (const float*)d_in[0];
  const float* freq  = (const float*)d_in[1];
  const float* theta = (const float*)d_in[2];
  const float* psi   = (const float*)d_in[3];
  const float* sigma = (const float*)d_in[4];
  const float* gamma = (const float*)d_in[5];
  const float* beta  = (const float*)d_in[6];
  float* out = (float*)d_out;

  __hip_bfloat16* wsw = (__hip_bfloat16*)d_ws;
  float2* part = (float2*)((char*)d_ws + 262144);
  float2* ab   = (float2*)((char*)d_ws + 786432);

  gabor_kernel<<<32, 256, 0, stream>>>(freq, theta, psi, sigma, wsw);
  conv_mfma<<<dim3(16, BATCH), 512, 0, stream>>>(x, (const char*)d_ws, out, part);
  stats_kernel<<<COUT, 256, 0, stream>>>(part, gamma, beta, ab);
  norm_kernel<<<4194304 / 256, 256, 0, stream>>>(out, ab);
}

// Round 10
// 78.911 us; speedup vs baseline: 1.8396x; 1.0157x over previous
//
#include <hip/hip_runtime.h>
#include <hip/hip_bf16.h>

#define BATCH 32
#define CIN   64
#define COUT  128
#define HIN   128
#define WIN   128
#define HOUT  64
#define WOUT  64

typedef unsigned int u32;
typedef __attribute__((ext_vector_type(8))) short short8;
typedef __attribute__((ext_vector_type(4))) float f32x4;

// ---------------- ws layout ----------------
// wsW  : byte      0 .. 262144 : bf16 weights, SWIZZLED image, 16 chunks * 16384 B
//        chunk byte P = o*128 + (((4*(k6>>5) + ((k6>>3)&3)) ^ (o&7))*16) + (k6&7)*2
// part : byte 262144 .. 786432 : [128][512] float2 partial sums
// ab   : byte 786432 .. 787456 : [128] float2 (scale, shift)

__device__ inline unsigned short f2bf(float v) {
  __hip_bfloat16 h = __float2bfloat16(v);
  return *reinterpret_cast<unsigned short*>(&h);
}
__device__ inline u32 pack2(float a, float b) {
  return (u32)f2bf(a) | ((u32)f2bf(b) << 16);
}

// ---------------- Kernel 1: Gabor filters -> swizzled bf16 image ----------------
// k = i*16 + kh*4 + kw ; chunk c = i>>2 ; k6 = (i&3)*16 + kh*4 + kw
// Image matches conv's swizzled ds_read_b128 addressing (identity global->LDS copy).
__global__ __launch_bounds__(256) void gabor_kernel(
    const float* __restrict__ freq, const float* __restrict__ theta,
    const float* __restrict__ psi,  const float* __restrict__ sigma,
    __hip_bfloat16* __restrict__ wsw) {
  int idx = blockIdx.x * 256 + threadIdx.x;     // 8192 = 128*64
  int o = idx >> 6, i = idx & 63;
  float f = freq[idx], t = theta[idx], p = psi[idx], s = sigma[idx];
  float ct = cosf(t), st = sinf(t);
  float se = s + 0.001f;
  float gsc = -0.5f / (se * se);
  float nrm = 1.0f / (2.0f * 3.14f * s * s);    // PI = 3.14 in the reference
  const float lin[4] = {-1.f, 0.f, 1.f, 2.f};
  int chunk = i >> 2;
  #pragma unroll
  for (int ky = 0; ky < 4; ++ky) {
    #pragma unroll
    for (int kx = 0; kx < 4; ++kx) {
      float xx = lin[kx], yy = lin[ky];
      float rx =  xx * ct + yy * st;
      float ry = -xx * st + yy * ct;
      float g = __expf(gsc * (rx * rx + ry * ry)) * cosf(f * rx + p) * nrm;
      int k6 = (i & 3) * 16 + ky * 4 + kx;
      int sub = 4 * (k6 >> 5) + ((k6 >> 3) & 3);
      int j = k6 & 7;
      int slot = sub ^ (o & 7);
      wsw[(chunk * 16384 + o * 128 + slot * 16 + j * 2) >> 1] = __float2bfloat16(g);
    }
  }
}

// ---------------- Kernel 2: implicit-GEMM conv via MFMA ----------------
// Block: 512 thr (8 waves, 2M x 4N). Tile M=128 x N=256 (4 oh x 64 ow).
// K loop: 16 chunks of 64 (4 input channels). A via global_load_lds (identity copy
// of the pre-swizzled image); X reg-staged with aligned float4 loads, +3 pad shift
// applied in LDS write addressing. Both double-buffered.
constexpr int XPITCH = 70;    // dwords per x-tile row (140 bf16; ci = iw+3)
constexpr int XCH    = 700;   // dwords per channel plane (10 rows)
constexpr int XBYTES = 11200; // 4 ch * 700 dw * 4 B
constexpr int NSLOT  = 1280;  // 4 ch * 10 rows * 32 aligned quads
// LDS: A0 @0, A1 @16384, X0 @32768, X1 @43968 ; total 55168

__global__ __launch_bounds__(512, 4) void conv_mfma(
    const float* __restrict__ x, const char* __restrict__ wsW,
    float* __restrict__ out, float2* __restrict__ part) {
  __shared__ __align__(16) char lds[55168];

  const int tid = threadIdx.x;
  const int l = tid & 63, w = tid >> 6;       // 8 waves
  const int wm = w & 1, wn = w >> 1;          // wm: M-half, wn: N-quarter (0..3)
  const int t4 = l >> 4, lcol = l & 15;
  const int khp = t4 & 1, ihalf = t4 >> 1;
  const int ohb = blockIdx.x, b = blockIdx.y;
  const int oh0 = ohb * 4;

  // ---- X staging precompute: 3 slots/thread, sg = tid + u*512 (covers 1280) ----
  bool act[3]; int xbyte[3]; const float* gp[3];
  #pragma unroll
  for (int u = 0; u < 3; ++u) {
    int sg = tid + u * 512;
    int r = sg >> 5, s = sg & 31;          // row r (0..39), aligned quad s (0..31)
    int ch = r / 10, row = r - ch * 10;
    int ih = oh0 * 2 - 1 + row;
    act[u] = (sg < NSLOT) && ((unsigned)ih < 128u);
    xbyte[u] = (ch * XCH + row * XPITCH) * 4 + s * 8;
    gp[u] = x + (((size_t)(b * 64 + ch) << 14) + (size_t)ih * 128 + 4 * s);
  }

  float4 xv[3];
  auto XLOAD = [&](int c) {
    #pragma unroll
    for (int u = 0; u < 3; ++u)
      if (act[u]) xv[u] = *(const float4*)(gp[u] + (size_t)c * 65536);
  };
  auto XWRITE = [&](int nb) {
    char* X = lds + 32768 + nb * XBYTES;
    #pragma unroll
    for (int u = 0; u < 3; ++u)
      if (act[u]) {
        char* pb = X + xbyte[u];
        *(unsigned short*)(pb + 6)  = f2bf(xv[u].x);           // ci 4s+3
        *(u32*)(pb + 8)             = pack2(xv[u].y, xv[u].z); // ci 4s+4,4s+5
        *(unsigned short*)(pb + 12) = f2bf(xv[u].w);           // ci 4s+6
      }
  };

  // ---- A staging: identity copy via global_load_lds, 2 x 1 KiB per wave ----
  auto ASTAGE = [&](int c, int nb) {
    const char* src = wsW + c * 16384 + w * 2048 + l * 16;
    char* dst = lds + nb * 16384 + w * 2048;     // wave-uniform base; HW adds lane*16
    __builtin_amdgcn_global_load_lds(
        (const __attribute__((address_space(1))) u32*)src,
        (__attribute__((address_space(3))) u32*)dst, 16, 0, 0);
    __builtin_amdgcn_global_load_lds(
        (const __attribute__((address_space(1))) u32*)(src + 1024),
        (__attribute__((address_space(3))) u32*)(dst + 1024), 16, 0, 0);
  };

  // ---- one-time zero fill of both X buffers (edges + OOB rows stay zero) ----
  {
    u32* X = (u32*)(lds + 32768);
    for (int i = tid; i < 2 * XBYTES / 4; i += 512) X[i] = 0;
  }

  f32x4 acc[4][4];
  #pragma unroll
  for (int mf = 0; mf < 4; ++mf)
    #pragma unroll
    for (int nf = 0; nf < 4; ++nf) acc[mf][nf] = {0.f, 0.f, 0.f, 0.f};

  // B-fragment dword offsets (within X buffer); nfb = 4*wn + nf in 0..15
  int bo[4];
  #pragma unroll
  for (int nf = 0; nf < 4; ++nf) {
    int nfb = 4 * wn + nf;
    bo[nf] = ihalf * XCH + khp * (2 * XPITCH) + lcol + 1 +
             (nfb >> 2) * (2 * XPITCH) + ((nfb & 3) << 4);
  }

  // A-fragment LDS offsets: row o = wm*64 + mf*16 + lcol, subtile (4*kk + t4),
  // swizzled: byte = o*128 + ((4*kk + t4) ^ (o&7))*16
  int ao[4][2];
  #pragma unroll
  for (int mf = 0; mf < 4; ++mf)
    #pragma unroll
    for (int kk = 0; kk < 2; ++kk)
      ao[mf][kk] = (wm * 64 + mf * 16 + lcol) * 128 +
                   (((4 * kk + t4) ^ (lcol & 7)) << 4);

  auto COMPUTE = [&](int cb) {
    const char* Ab = lds + cb * 16384;
    const u32* Xb = (const u32*)(lds + 32768 + cb * XBYTES);
    #pragma unroll
    for (int kk = 0; kk < 2; ++kk) {
      short8 af[4];
      #pragma unroll
      for (int mf = 0; mf < 4; ++mf)
        af[mf] = *(const short8*)(Ab + ao[mf][kk]);
      #pragma unroll
      for (int nf = 0; nf < 4; ++nf) {
        const u32* p = Xb + bo[nf] + kk * 1400;      // 2 channel planes
        union { u32 u[4]; short8 s8; } bu;
        bu.u[0] = p[0]; bu.u[1] = p[1];
        bu.u[2] = p[XPITCH]; bu.u[3] = p[XPITCH + 1];
        short8 bf = bu.s8;
        #pragma unroll
        for (int mf = 0; mf < 4; ++mf)
          acc[mf][nf] = __builtin_amdgcn_mfma_f32_16x16x32_bf16(af[mf], bf, acc[mf][nf], 0, 0, 0);
      }
    }
  };

  // ---- main loop: A+X double-buffered, loads issued early ----
  ASTAGE(0, 0); XLOAD(0);
  __syncthreads();                 // zero-fill visible before first X writes
  XWRITE(0);
  __syncthreads();                 // (vmcnt drained by compiler: A0 ready too)
  for (int c = 0; c < 16; ++c) {
    int cur = c & 1;
    if (c < 15) { ASTAGE(c + 1, cur ^ 1); XLOAD(c + 1); }  // in flight over COMPUTE
    COMPUTE(cur);
    if (c < 15) XWRITE(cur ^ 1);
    __syncthreads();
  }

  // ---- epilogue: conv output (C/D layout: col=lane&15, row=(lane>>4)*4+reg) ----
  size_t obase = ((size_t)b * 128) * 4096;
  #pragma unroll
  for (int mf = 0; mf < 4; ++mf)
    #pragma unroll
    for (int nf = 0; nf < 4; ++nf) {
      int nfb = 4 * wn + nf;
      int oh = oh0 + (nfb >> 2), ow = ((nfb & 3) << 4) + lcol;
      #pragma unroll
      for (int r = 0; r < 4; ++r) {
        int o = wm * 64 + mf * 16 + t4 * 4 + r;
        out[obase + (size_t)o * 4096 + oh * 64 + ow] = acc[mf][nf][r];
      }
    }

  // ---- deterministic per-block (sum, sumsq) partials ----
  float* ps = (float*)lds;    // A0 region dead after last barrier
  #pragma unroll
  for (int mf = 0; mf < 4; ++mf)
    #pragma unroll
    for (int r = 0; r < 4; ++r) {
      float s1 = 0.f, s2 = 0.f;
      #pragma unroll
      for (int nf = 0; nf < 4; ++nf) { float v = acc[mf][nf][r]; s1 += v; s2 += v * v; }
      #pragma unroll
      for (int d = 1; d < 16; d <<= 1) { s1 += __shfl_xor(s1, d); s2 += __shfl_xor(s2, d); }
      if (lcol == 0) {
        int o = wm * 64 + mf * 16 + t4 * 4 + r;
        ps[o * 8 + wn * 2 + 0] = s1;
        ps[o * 8 + wn * 2 + 1] = s2;
      }
    }
  __syncthreads();
  if (tid < 128) {
    float s1 = 0.f, s2 = 0.f;
    #pragma unroll
    for (int q = 0; q < 4; ++q) {
      s1 += ps[tid * 8 + q * 2 + 0];
      s2 += ps[tid * 8 + q * 2 + 1];
    }
    part[(size_t)tid * 512 + b * 16 + ohb] = make_float2(s1, s2);
  }
}

// ---------------- Kernel 3: per-channel stats -> (a,b) ----------------
__global__ __launch_bounds__(256) void stats_kernel(
    const float2* __restrict__ part, const float* __restrict__ gamma,
    const float* __restrict__ beta, float2* __restrict__ ab) {
  int o = blockIdx.x;
  int tid = threadIdx.x;
  float s1 = 0.f, s2 = 0.f;
  #pragma unroll
  for (int t = 0; t < 2; ++t) {
    float2 p = part[(size_t)o * 512 + tid + t * 256];
    s1 += p.x; s2 += p.y;
  }
  __shared__ float r1[256], r2[256];
  r1[tid] = s1; r2[tid] = s2;
  __syncthreads();
  for (int off = 128; off > 0; off >>= 1) {
    if (tid < off) { r1[tid] += r1[tid + off]; r2[tid] += r2[tid + off]; }
    __syncthreads();
  }
  if (tid == 0) {
    const float N = (float)BATCH * HOUT * WOUT;   // 131072
    float mean = r1[0] / N;
    float var  = r2[0] / N - mean * mean;
    float inv  = rsqrtf(var + 1e-5f);
    float a = gamma[o] * inv;
    float bb = beta[o] - mean * a;
    ab[o] = make_float2(a, bb);
  }
}

// ---------------- Kernel 4: normalize + leaky ReLU (in-place, float4) ----------------
__global__ __launch_bounds__(256) void norm_kernel(
    float* __restrict__ out, const float2* __restrict__ ab) {
  size_t idx = (size_t)blockIdx.x * 256 + threadIdx.x;   // float4 index
  int o = (int)((idx >> 10) & (COUT - 1));               // 1024 float4 per (b,o) plane
  float2 s = ab[o];
  float4 v = reinterpret_cast<float4*>(out)[idx];
  v.x = fmaf(v.x, s.x, s.y);
  v.y = fmaf(v.y, s.x, s.y);
  v.z = fmaf(v.z, s.x, s.y);
  v.w = fmaf(v.w, s.x, s.y);
  v.x = v.x >= 0.f ? v.x : 0.1f * v.x;
  v.y = v.y >= 0.f ? v.y : 0.1f * v.y;
  v.z = v.z >= 0.f ? v.z : 0.1f * v.z;
  v.w = v.w >= 0.f ? v.w : 0.1f * v.w;
  reinterpret_cast<float4*>(out)[idx] = v;
}

extern "C" void kernel_launch(void* const* d_in, const int* in_sizes, int n_in,
                              void* d_out, int out_size, void* d_ws, size_t ws_size,
                              hipStream_t stream) {
  const float* x     = (const float*)d_in[0];
  const float* freq  = (const float*)d_in[1];
  const float* theta = (const float*)d_in[2];
  const float* psi   = (const float*)d_in[3];
  const float* sigma = (const float*)d_in[4];
  const float* gamma = (const float*)d_in[5];
  const float* beta  = (const float*)d_in[6];
  float* out = (float*)d_out;

  __hip_bfloat16* wsw = (__hip_bfloat16*)d_ws;
  float2* part = (float2*)((char*)d_ws + 262144);
  float2* ab   = (float2*)((char*)d_ws + 786432);

  gabor_kernel<<<32, 256, 0, stream>>>(freq, theta, psi, sigma, wsw);
  conv_mfma<<<dim3(16, BATCH), 512, 0, stream>>>(x, (const char*)d_ws, out, part);
  stats_kernel<<<COUT, 256, 0, stream>>>(part, gamma, beta, ab);
  norm_kernel<<<4194304 / 256, 256, 0, stream>>>(out, ab);
}

// Round 11
// 77.277 us; speedup vs baseline: 1.8785x; 1.0211x over previous
//
#include <hip/hip_runtime.h>
#include <hip/hip_bf16.h>

#define BATCH 32
#define CIN   64
#define COUT  128
#define HIN   128
#define WIN   128
#define HOUT  64
#define WOUT  64

typedef unsigned int u32;
typedef __attribute__((ext_vector_type(8))) short short8;
typedef __attribute__((ext_vector_type(4))) float f32x4;

// ---------------- ws layout ----------------
// wsW  : byte      0 .. 262144 : bf16 weights, SWIZZLED image, 16 chunks * 16384 B
//        chunk byte P = o*128 + (((4*(k6>>5) + ((k6>>3)&3)) ^ (o&7))*16) + (k6&7)*2
// part : byte 262144 .. 524288 : [128][256] float2 partial sums
// ab   : byte 786432 .. 787456 : [128] float2 (scale, shift)

__device__ inline unsigned short f2bf(float v) {
  __hip_bfloat16 h = __float2bfloat16(v);
  return *reinterpret_cast<unsigned short*>(&h);
}
__device__ inline u32 pack2(float a, float b) {
  return (u32)f2bf(a) | ((u32)f2bf(b) << 16);
}

// ---------------- Kernel 1: Gabor filters -> swizzled bf16 image (verified) ----------------
__global__ __launch_bounds__(256) void gabor_kernel(
    const float* __restrict__ freq, const float* __restrict__ theta,
    const float* __restrict__ psi,  const float* __restrict__ sigma,
    __hip_bfloat16* __restrict__ wsw) {
  int idx = blockIdx.x * 256 + threadIdx.x;     // 8192 = 128*64
  int o = idx >> 6, i = idx & 63;
  float f = freq[idx], t = theta[idx], p = psi[idx], s = sigma[idx];
  float ct = cosf(t), st = sinf(t);
  float se = s + 0.001f;
  float gsc = -0.5f / (se * se);
  float nrm = 1.0f / (2.0f * 3.14f * s * s);    // PI = 3.14 in the reference
  const float lin[4] = {-1.f, 0.f, 1.f, 2.f};
  int chunk = i >> 2;
  #pragma unroll
  for (int ky = 0; ky < 4; ++ky) {
    #pragma unroll
    for (int kx = 0; kx < 4; ++kx) {
      float xx = lin[kx], yy = lin[ky];
      float rx =  xx * ct + yy * st;
      float ry = -xx * st + yy * ct;
      float g = __expf(gsc * (rx * rx + ry * ry)) * cosf(f * rx + p) * nrm;
      int k6 = (i & 3) * 16 + ky * 4 + kx;
      int sub = 4 * (k6 >> 5) + ((k6 >> 3) & 3);
      int j = k6 & 7;
      int slot = sub ^ (o & 7);
      wsw[(chunk * 16384 + o * 128 + slot * 16 + j * 2) >> 1] = __float2bfloat16(g);
    }
  }
}

// ---------------- Kernel 2: implicit-GEMM conv via MFMA ----------------
// Block: 1024 thr (16 waves, 2M x 8N). Tile M=128 x N=512 (8 oh x 64 ow).
// Grid: 8 ohb x 32 b = 256 blocks. K loop: 16 chunks of 64 (4 input channels).
// A via global_load_lds (identity copy of pre-swizzled image); X reg-staged with
// aligned float4 loads, +3 pad shift applied in LDS write addressing.
constexpr int XPITCH = 70;    // dwords per x-tile row (140 bf16; ci = iw+3)
constexpr int XROWS  = 18;    // ih rows per channel (8 oh -> 18 with halo)
constexpr int XCH    = 1260;  // dwords per channel plane (18 rows * 70)
constexpr int XBYTES = 20160; // 4 ch * 1260 dw * 4 B
constexpr int NSLOT  = 2304;  // 4 ch * 18 rows * 32 aligned quads
// LDS: A0 @0, A1 @16384, X0 @32768, X1 @52928 ; total 73088

__global__ __launch_bounds__(1024, 4) void conv_mfma(
    const float* __restrict__ x, const char* __restrict__ wsW,
    float* __restrict__ out, float2* __restrict__ part) {
  __shared__ __align__(16) char lds[73088];

  const int tid = threadIdx.x;
  const int l = tid & 63, w = tid >> 6;       // 16 waves
  const int wm = w & 1, wn = w >> 1;          // wm: M-half, wn: N-eighth (0..7)
  const int t4 = l >> 4, lcol = l & 15;
  const int khp = t4 & 1, ihalf = t4 >> 1;
  const int ohb = blockIdx.x, b = blockIdx.y;
  const int oh0 = ohb * 8;

  // ---- X staging precompute: 3 slots/thread, sg = tid + u*1024 (covers 2304) ----
  bool act[3]; int xbyte[3]; const float* gp[3];
  #pragma unroll
  for (int u = 0; u < 3; ++u) {
    int sg = tid + u * 1024;
    int r = sg >> 5, s = sg & 31;          // row-slot r (0..95), aligned quad s
    int ch = r / XROWS, row = r - ch * XROWS;
    int ih = oh0 * 2 - 1 + row;
    act[u] = (sg < NSLOT) && ((unsigned)ih < 128u);
    xbyte[u] = (ch * XCH + row * XPITCH) * 4 + s * 8;
    gp[u] = x + (((size_t)(b * 64 + ch) << 14) + (size_t)ih * 128 + 4 * s);
  }

  float4 xv[3];
  auto XLOAD = [&](int c) {
    #pragma unroll
    for (int u = 0; u < 3; ++u)
      if (act[u]) xv[u] = *(const float4*)(gp[u] + (size_t)c * 65536);
  };
  auto XWRITE = [&](int nb) {
    char* X = lds + 32768 + nb * XBYTES;
    #pragma unroll
    for (int u = 0; u < 3; ++u)
      if (act[u]) {
        char* pb = X + xbyte[u];
        *(unsigned short*)(pb + 6)  = f2bf(xv[u].x);           // ci 4s+3
        *(u32*)(pb + 8)             = pack2(xv[u].y, xv[u].z); // ci 4s+4,4s+5
        *(unsigned short*)(pb + 12) = f2bf(xv[u].w);           // ci 4s+6
      }
  };

  // ---- A staging: identity copy via global_load_lds, 1 KiB per wave ----
  auto ASTAGE = [&](int c, int nb) {
    const char* src = wsW + c * 16384 + w * 1024 + l * 16;
    char* dst = lds + nb * 16384 + w * 1024;     // wave-uniform base; HW adds lane*16
    __builtin_amdgcn_global_load_lds(
        (const __attribute__((address_space(1))) u32*)src,
        (__attribute__((address_space(3))) u32*)dst, 16, 0, 0);
  };

  // ---- one-time zero fill of both X buffers (edges + OOB rows stay zero) ----
  {
    u32* X = (u32*)(lds + 32768);
    for (int i = tid; i < 2 * XBYTES / 4; i += 1024) X[i] = 0;
  }

  f32x4 acc[4][4];
  #pragma unroll
  for (int mf = 0; mf < 4; ++mf)
    #pragma unroll
    for (int nf = 0; nf < 4; ++nf) acc[mf][nf] = {0.f, 0.f, 0.f, 0.f};

  // B-fragment dword offsets (within X buffer); nfb = 4*wn + nf in 0..31
  int bo[4];
  #pragma unroll
  for (int nf = 0; nf < 4; ++nf) {
    int nfb = 4 * wn + nf;
    bo[nf] = ihalf * XCH + khp * (2 * XPITCH) + lcol + 1 +
             (nfb >> 2) * (2 * XPITCH) + ((nfb & 3) << 4);
  }

  // A-fragment LDS offsets: row o = wm*64 + mf*16 + lcol, subtile (4*kk + t4),
  // swizzled: byte = o*128 + ((4*kk + t4) ^ (o&7))*16
  int ao[4][2];
  #pragma unroll
  for (int mf = 0; mf < 4; ++mf)
    #pragma unroll
    for (int kk = 0; kk < 2; ++kk)
      ao[mf][kk] = (wm * 64 + mf * 16 + lcol) * 128 +
                   (((4 * kk + t4) ^ (lcol & 7)) << 4);

  auto COMPUTE = [&](int cb) {
    const char* Ab = lds + cb * 16384;
    const u32* Xb = (const u32*)(lds + 32768 + cb * XBYTES);
    __builtin_amdgcn_s_setprio(1);
    #pragma unroll
    for (int kk = 0; kk < 2; ++kk) {
      short8 af[4];
      #pragma unroll
      for (int mf = 0; mf < 4; ++mf)
        af[mf] = *(const short8*)(Ab + ao[mf][kk]);
      #pragma unroll
      for (int nf = 0; nf < 4; ++nf) {
        const u32* p = Xb + bo[nf] + kk * (2 * XCH);   // 2 channel planes
        union { u32 u[4]; short8 s8; } bu;
        bu.u[0] = p[0]; bu.u[1] = p[1];
        bu.u[2] = p[XPITCH]; bu.u[3] = p[XPITCH + 1];
        short8 bf = bu.s8;
        #pragma unroll
        for (int mf = 0; mf < 4; ++mf)
          acc[mf][nf] = __builtin_amdgcn_mfma_f32_16x16x32_bf16(af[mf], bf, acc[mf][nf], 0, 0, 0);
      }
    }
    __builtin_amdgcn_s_setprio(0);
  };

  // ---- main loop: A+X double-buffered, loads issued early ----
  ASTAGE(0, 0); XLOAD(0);
  __syncthreads();                 // zero-fill visible before first X writes
  XWRITE(0);
  __syncthreads();                 // vmcnt drained: A0 ready too
  for (int c = 0; c < 16; ++c) {
    int cur = c & 1;
    if (c < 15) { ASTAGE(c + 1, cur ^ 1); XLOAD(c + 1); }  // in flight over COMPUTE
    COMPUTE(cur);
    if (c < 15) XWRITE(cur ^ 1);
    __syncthreads();
  }

  // ---- epilogue: conv output (C/D layout: col=lane&15, row=(lane>>4)*4+reg) ----
  size_t obase = ((size_t)b * 128) * 4096;
  #pragma unroll
  for (int mf = 0; mf < 4; ++mf)
    #pragma unroll
    for (int nf = 0; nf < 4; ++nf) {
      int nfb = 4 * wn + nf;
      int oh = oh0 + (nfb >> 2), ow = ((nfb & 3) << 4) + lcol;
      #pragma unroll
      for (int r = 0; r < 4; ++r) {
        int o = wm * 64 + mf * 16 + t4 * 4 + r;
        out[obase + (size_t)o * 4096 + oh * 64 + ow] = acc[mf][nf][r];
      }
    }

  // ---- deterministic per-block (sum, sumsq) partials ----
  float* ps = (float*)lds;    // A0 region dead after last barrier; [128 o][8 wn][2]
  #pragma unroll
  for (int mf = 0; mf < 4; ++mf)
    #pragma unroll
    for (int r = 0; r < 4; ++r) {
      float s1 = 0.f, s2 = 0.f;
      #pragma unroll
      for (int nf = 0; nf < 4; ++nf) { float v = acc[mf][nf][r]; s1 += v; s2 += v * v; }
      #pragma unroll
      for (int d = 1; d < 16; d <<= 1) { s1 += __shfl_xor(s1, d); s2 += __shfl_xor(s2, d); }
      if (lcol == 0) {
        int o = wm * 64 + mf * 16 + t4 * 4 + r;
        ps[o * 16 + wn * 2 + 0] = s1;
        ps[o * 16 + wn * 2 + 1] = s2;
      }
    }
  __syncthreads();
  if (tid < 128) {
    float s1 = 0.f, s2 = 0.f;
    #pragma unroll
    for (int q = 0; q < 8; ++q) {
      s1 += ps[tid * 16 + q * 2 + 0];
      s2 += ps[tid * 16 + q * 2 + 1];
    }
    part[(size_t)tid * 256 + b * 8 + ohb] = make_float2(s1, s2);
  }
}

// ---------------- Kernel 3: per-channel stats -> (a,b) ----------------
__global__ __launch_bounds__(256) void stats_kernel(
    const float2* __restrict__ part, const float* __restrict__ gamma,
    const float* __restrict__ beta, float2* __restrict__ ab) {
  int o = blockIdx.x;
  int tid = threadIdx.x;
  float2 p = part[(size_t)o * 256 + tid];
  float s1 = p.x, s2 = p.y;
  __shared__ float r1[256], r2[256];
  r1[tid] = s1; r2[tid] = s2;
  __syncthreads();
  for (int off = 128; off > 0; off >>= 1) {
    if (tid < off) { r1[tid] += r1[tid + off]; r2[tid] += r2[tid + off]; }
    __syncthreads();
  }
  if (tid == 0) {
    const float N = (float)BATCH * HOUT * WOUT;   // 131072
    float mean = r1[0] / N;
    float var  = r2[0] / N - mean * mean;
    float inv  = rsqrtf(var + 1e-5f);
    float a = gamma[o] * inv;
    float bb = beta[o] - mean * a;
    ab[o] = make_float2(a, bb);
  }
}

// ---------------- Kernel 4: normalize + leaky ReLU (in-place, float4) ----------------
__global__ __launch_bounds__(256) void norm_kernel(
    float* __restrict__ out, const float2* __restrict__ ab) {
  size_t idx = (size_t)blockIdx.x * 256 + threadIdx.x;   // float4 index
  int o = (int)((idx >> 10) & (COUT - 1));               // 1024 float4 per (b,o) plane
  float2 s = ab[o];
  float4 v = reinterpret_cast<float4*>(out)[idx];
  v.x = fmaf(v.x, s.x, s.y);
  v.y = fmaf(v.y, s.x, s.y);
  v.z = fmaf(v.z, s.x, s.y);
  v.w = fmaf(v.w, s.x, s.y);
  v.x = v.x >= 0.f ? v.x : 0.1f * v.x;
  v.y = v.y >= 0.f ? v.y : 0.1f * v.y;
  v.z = v.z >= 0.f ? v.z : 0.1f * v.z;
  v.w = v.w >= 0.f ? v.w : 0.1f * v.w;
  reinterpret_cast<float4*>(out)[idx] = v;
}

extern "C" void kernel_launch(void* const* d_in, const int* in_sizes, int n_in,
                              void* d_out, int out_size, void* d_ws, size_t ws_size,
                              hipStream_t stream) {
  const float* x     = (const float*)d_in[0];
  const float* freq  = (const float*)d_in[1];
  const float* theta = (const float*)d_in[2];
  const float* psi   = (const float*)d_in[3];
  const float* sigma = (const float*)d_in[4];
  const float* gamma = (const float*)d_in[5];
  const float* beta  = (const float*)d_in[6];
  float* out = (float*)d_out;

  __hip_bfloat16* wsw = (__hip_bfloat16*)d_ws;
  float2* part = (float2*)((char*)d_ws + 262144);
  float2* ab   = (float2*)((char*)d_ws + 786432);

  gabor_kernel<<<32, 256, 0, stream>>>(freq, theta, psi, sigma, wsw);
  conv_mfma<<<dim3(8, BATCH), 1024, 0, stream>>>(x, (const char*)d_ws, out, part);
  stats_kernel<<<COUT, 256, 0, stream>>>(part, gamma, beta, ab);
  norm_kernel<<<4194304 / 256, 256, 0, stream>>>(out, ab);
}